// Round 1
// baseline (1915.915 us; speedup 1.0000x reference)
//
#include <hip/hip_runtime.h>
#include <hip/hip_bf16.h>
#include <math.h>

typedef __attribute__((ext_vector_type(8))) short short8;
typedef __attribute__((ext_vector_type(4))) float f32x4;

__device__ __forceinline__ short f2bf(float f){
  unsigned u = __float_as_uint(f);
  u = (u + 0x7FFFu + ((u >> 16) & 1u)) >> 16;
  return (short)u;
}

// ---------------- weight prep ----------------
__global__ void cast_bf16_kernel(const float* __restrict__ s, short* __restrict__ d, int n){
  int i = blockIdx.x * 256 + threadIdx.x;
  if (i < n) d[i] = f2bf(s[i]);
}

// ff_w1 (4,2730,512) -> W1p (4,2816,512), rows interleaved: 2j <- u_j (row j), 2j+1 <- gate_j (row 1365+j)
__global__ void w1p_kernel(const float* __restrict__ s, short* __restrict__ d){
  int i = blockIdx.x * 256 + threadIdx.x;   // 4*2816*512
  int c  = i & 511;
  int rl = i >> 9;
  int r  = rl % 2816;
  int l  = rl / 2816;
  float v = 0.f;
  if (r < 2730){
    int sr = (r & 1) ? (1365 + (r >> 1)) : (r >> 1);
    v = s[((size_t)l * 2730 + sr) * 512 + c];
  }
  d[i] = f2bf(v);
}

// ff_w2 (4,512,1365) -> W2p (4,512,1408), K zero-padded
__global__ void w2p_kernel(const float* __restrict__ s, short* __restrict__ d){
  int i = blockIdx.x * 256 + threadIdx.x;   // 4*512*1408
  int c = i % 1408;
  int r = i / 1408;                          // l*512 + row
  float v = (c < 1365) ? s[(size_t)r * 1365 + c] : 0.f;
  d[i] = f2bf(v);
}

// ---------------- embedding ----------------
__global__ void embed_kernel(const float* __restrict__ x, const float* __restrict__ w,
                             const float* __restrict__ bias, float* __restrict__ hf,
                             short* __restrict__ hb){
  long i = (long)blockIdx.x * 256 + threadIdx.x;  // 32768*512
  long row = i >> 9; int e = (int)(i & 511);
  float v = x[row] * w[e] + bias[e];
  hf[i] = v;
  hb[i] = f2bf(v);
}

// ---------------- GEMM: C = A(MxK bf16) * B(NxK bf16)^T ----------------
// EPI: 0 = store bf16 to Cbf(ldcb); 1 = Cres(512) += acc (f32);
//      2 = Cres += acc, also store bf16 to Cbf(512); 3 = GEGLU pairs -> Cbf(ldcb)
template<int EPI>
__global__ __launch_bounds__(256, 2)
void gemm_bt(const short* __restrict__ A, const short* __restrict__ B, int K,
             float* __restrict__ Cres, short* __restrict__ Cbf, int ldcb)
{
  __shared__ short As[128 * 64];
  __shared__ short Bs[128 * 64];
  const int tid  = threadIdx.x;
  const int lane = tid & 63;
  const int w    = tid >> 6;
  const int wr   = (w >> 1) * 64, wc = (w & 1) * 64;
  const long tm = (long)blockIdx.y * 128, tn = (long)blockIdx.x * 128;

  f32x4 acc[4][4];
  #pragma unroll
  for (int i = 0; i < 4; i++)
    #pragma unroll
    for (int j = 0; j < 4; j++)
      acc[i][j] = (f32x4){0.f, 0.f, 0.f, 0.f};

  const int row_s = tid >> 3;   // staging: chunk q = tid + r*256 -> row = row_s + r*32, col16B = c_s
  const int c_s   = tid & 7;

  for (int k0 = 0; k0 < K; k0 += 64){
    __syncthreads();
    #pragma unroll
    for (int r = 0; r < 4; r++){
      int row = row_s + r * 32;
      short8 av = *(const short8*)(A + (tm + row) * K + k0 + c_s * 8);
      short8 bv = *(const short8*)(B + (tn + row) * K + k0 + c_s * 8);
      int off = (row * 128 + c_s * 16) ^ ((row & 7) << 4);
      *(short8*)((char*)As + off) = av;
      *(short8*)((char*)Bs + off) = bv;
    }
    __syncthreads();
    #pragma unroll
    for (int kk = 0; kk < 2; kk++){
      short8 a[4], b[4];
      int ac = (kk * 32 + (lane >> 4) * 8) * 2;
      #pragma unroll
      for (int i = 0; i < 4; i++){
        int ar = wr + i * 16 + (lane & 15);
        a[i] = *(const short8*)((char*)As + ((ar * 128 + ac) ^ ((ar & 7) << 4)));
        int br = wc + i * 16 + (lane & 15);
        b[i] = *(const short8*)((char*)Bs + ((br * 128 + ac) ^ ((br & 7) << 4)));
      }
      #pragma unroll
      for (int i = 0; i < 4; i++)
        #pragma unroll
        for (int j = 0; j < 4; j++)
          acc[i][j] = __builtin_amdgcn_mfma_f32_16x16x32_bf16(a[i], b[j], acc[i][j], 0, 0, 0);
    }
  }

  #pragma unroll
  for (int i = 0; i < 4; i++){
    #pragma unroll
    for (int j = 0; j < 4; j++){
      #pragma unroll
      for (int v = 0; v < 4; v++){
        long row = tm + wr + i * 16 + (lane >> 4) * 4 + v;
        long col = tn + wc + j * 16 + (lane & 15);
        float x = acc[i][j][v];
        if (EPI == 0){
          Cbf[row * ldcb + col] = f2bf(x);
        } else if (EPI == 1){
          float rr = x + Cres[row * 512 + col];
          Cres[row * 512 + col] = rr;
        } else if (EPI == 2){
          float rr = x + Cres[row * 512 + col];
          Cres[row * 512 + col] = rr;
          Cbf[row * 512 + col] = f2bf(rr);
        } else {
          float other = __shfl_xor(x, 1);
          if ((lane & 1) == 0){
            float gate = other;
            float gg = 0.5f * gate * (1.f + erff(gate * 0.70710678118f));
            Cbf[row * ldcb + (col >> 1)] = f2bf(x * gg);
          }
        }
      }
    }
  }
}

// ---------------- local attention ----------------
// grid (32 windows, 8 heads, 8 batch), 256 threads (4 waves x 32 q-rows)
__global__ __launch_bounds__(256, 2)
void attn_kernel(const short* __restrict__ qkv, short* __restrict__ o)
{
  __shared__ short Ks[128 * 64];     // swizzled [key][d]
  __shared__ short Vt[64 * 136];     // [d][key], stride 136
  __shared__ short Ps[4 * 32 * 128]; // per-wave swizzled P
  const int win = blockIdx.x, hh = blockIdx.y, b = blockIdx.z;
  const int tid = threadIdx.x, lane = tid & 63, w = tid >> 6;
  const long qrow0 = (long)b * 4096 + (long)win * 128;

  // Q fragments straight from global (A-operand layout == 8 contiguous d per lane)
  short8 qf[2][2];
  #pragma unroll
  for (int i = 0; i < 2; i++)
    #pragma unroll
    for (int kk = 0; kk < 2; kk++)
      qf[i][kk] = *(const short8*)(qkv + (qrow0 + w * 32 + i * 16 + (lane & 15)) * 1536
                                   + hh * 64 + kk * 32 + (lane >> 4) * 8);

  f32x4 oacc[2][4];
  #pragma unroll
  for (int i = 0; i < 2; i++)
    #pragma unroll
    for (int j = 0; j < 4; j++)
      oacc[i][j] = (f32x4){0.f, 0.f, 0.f, 0.f};
  float rs[2][4];
  #pragma unroll
  for (int i = 0; i < 2; i++)
    #pragma unroll
    for (int v = 0; v < 4; v++)
      rs[i][v] = 0.f;

  const int row_s = tid >> 3, c_s = tid & 7;
  for (int cc = 0; cc < 3; cc++){
    int kw = win - 1 + cc;
    if (kw < 0 || kw >= 32) continue;     // uniform per block
    const long krow0 = (long)b * 4096 + (long)kw * 128;
    __syncthreads();
    #pragma unroll
    for (int r = 0; r < 4; r++){
      int row = row_s + r * 32;
      const short* src = qkv + (krow0 + row) * 1536 + hh * 64;
      short8 kv = *(const short8*)(src + 512 + c_s * 8);
      *(short8*)((char*)Ks + ((row * 128 + c_s * 16) ^ ((row & 7) << 4))) = kv;
      short8 vv = *(const short8*)(src + 1024 + c_s * 8);
      #pragma unroll
      for (int e = 0; e < 8; e++) Vt[(c_s * 8 + e) * 136 + row] = vv[e];
    }
    __syncthreads();

    // QK^T
    f32x4 sacc[2][8];
    #pragma unroll
    for (int i = 0; i < 2; i++)
      #pragma unroll
      for (int j = 0; j < 8; j++)
        sacc[i][j] = (f32x4){0.f, 0.f, 0.f, 0.f};
    #pragma unroll
    for (int kk = 0; kk < 2; kk++){
      short8 bb[8];
      int ac = (kk * 32 + (lane >> 4) * 8) * 2;
      #pragma unroll
      for (int j = 0; j < 8; j++){
        int br = j * 16 + (lane & 15);
        bb[j] = *(const short8*)((char*)Ks + ((br * 128 + ac) ^ ((br & 7) << 4)));
      }
      #pragma unroll
      for (int i = 0; i < 2; i++)
        #pragma unroll
        for (int j = 0; j < 8; j++)
          sacc[i][j] = __builtin_amdgcn_mfma_f32_16x16x32_bf16(qf[i][kk], bb[j], sacc[i][j], 0, 0, 0);
    }

    // P = exp(s/8), row sums, transpose P through per-wave LDS
    short* myPs = Ps + w * 32 * 128;
    float psum[2][4];
    #pragma unroll
    for (int i = 0; i < 2; i++)
      #pragma unroll
      for (int v = 0; v < 4; v++)
        psum[i][v] = 0.f;
    #pragma unroll
    for (int i = 0; i < 2; i++)
      #pragma unroll
      for (int j = 0; j < 8; j++)
        #pragma unroll
        for (int v = 0; v < 4; v++){
          float p = expf(0.125f * sacc[i][j][v]);
          psum[i][v] += p;
          int prow = i * 16 + (lane >> 4) * 4 + v;
          int pcb  = (j * 16 + (lane & 15)) * 2;
          *(short*)((char*)myPs + ((prow * 256 + pcb) ^ ((prow & 7) << 4))) = f2bf(p);
        }
    #pragma unroll
    for (int i = 0; i < 2; i++)
      #pragma unroll
      for (int v = 0; v < 4; v++){
        float s = psum[i][v];
        s += __shfl_xor(s, 1); s += __shfl_xor(s, 2);
        s += __shfl_xor(s, 4); s += __shfl_xor(s, 8);
        rs[i][v] += s;
      }
    __syncthreads();

    // PV
    #pragma unroll
    for (int kk = 0; kk < 4; kk++){
      short8 pa[2], vb[4];
      int kb = (kk * 32 + (lane >> 4) * 8) * 2;
      #pragma unroll
      for (int i = 0; i < 2; i++){
        int pr = i * 16 + (lane & 15);
        pa[i] = *(const short8*)((char*)myPs + ((pr * 256 + kb) ^ ((pr & 7) << 4)));
      }
      #pragma unroll
      for (int j = 0; j < 4; j++){
        int vr = j * 16 + (lane & 15);
        vb[j] = *(const short8*)((char*)Vt + (vr * 272 + kb));
      }
      #pragma unroll
      for (int i = 0; i < 2; i++)
        #pragma unroll
        for (int j = 0; j < 4; j++)
          oacc[i][j] = __builtin_amdgcn_mfma_f32_16x16x32_bf16(pa[i], vb[j], oacc[i][j], 0, 0, 0);
    }
  }

  #pragma unroll
  for (int i = 0; i < 2; i++)
    #pragma unroll
    for (int j = 0; j < 4; j++)
      #pragma unroll
      for (int v = 0; v < 4; v++){
        long row = qrow0 + w * 32 + i * 16 + (lane >> 4) * 4 + v;
        int col = hh * 64 + j * 16 + (lane & 15);
        o[row * 512 + col] = f2bf(oacc[i][j][v] / rs[i][v]);
      }
}

// ---------------- layernorm (one wave per row) ----------------
__global__ __launch_bounds__(256)
void ln_kernel(const float* __restrict__ h, const float* __restrict__ g,
               const float* __restrict__ be, short* __restrict__ y)
{
  long row = (long)blockIdx.x * 4 + (threadIdx.x >> 6);
  int lane = threadIdx.x & 63;
  const float* x = h + row * 512 + lane * 8;
  float4 a0 = *(const float4*)x;
  float4 a1 = *(const float4*)(x + 4);
  float v[8] = {a0.x, a0.y, a0.z, a0.w, a1.x, a1.y, a1.z, a1.w};
  float s = 0.f, sq = 0.f;
  #pragma unroll
  for (int j = 0; j < 8; j++){ s += v[j]; sq += v[j] * v[j]; }
  #pragma unroll
  for (int m = 1; m <= 32; m <<= 1){ s += __shfl_xor(s, m); sq += __shfl_xor(sq, m); }
  float mu = s * (1.f / 512.f);
  float var = sq * (1.f / 512.f) - mu * mu;
  float rstd = rsqrtf(var + 1e-5f);
  short* yo = y + row * 512 + lane * 8;
  #pragma unroll
  for (int j = 0; j < 8; j++){
    int c = lane * 8 + j;
    yo[j] = f2bf((v[j] - mu) * rstd * g[c] + be[c]);
  }
}

// ---------------- mean pool + classifier ----------------
__global__ void pool_partial(const float* __restrict__ h, float* __restrict__ part){
  int b = blockIdx.x, ch = blockIdx.y, t = threadIdx.x;
  float s0 = 0.f, s1 = 0.f;
  const float* base = h + ((long)b * 4096 + ch * 128) * 512;
  for (int n = 0; n < 128; n++){
    s0 += base[(long)n * 512 + t];
    s1 += base[(long)n * 512 + t + 256];
  }
  part[((b * 32 + ch) * 512) + t] = s0;
  part[((b * 32 + ch) * 512) + t + 256] = s1;
}

__global__ void pool_proj(const float* __restrict__ part, const float* __restrict__ pw,
                          const float* __restrict__ pb, float* __restrict__ out){
  __shared__ float pooled[512];
  __shared__ float red[4];
  int b = blockIdx.x, t = threadIdx.x;
  int lane = t & 63, w = t >> 6;
  float s0 = 0.f, s1 = 0.f;
  for (int ch = 0; ch < 32; ch++){
    s0 += part[((b * 32 + ch) * 512) + t];
    s1 += part[((b * 32 + ch) * 512) + t + 256];
  }
  pooled[t] = s0 * (1.f / 4096.f);
  pooled[t + 256] = s1 * (1.f / 4096.f);
  __syncthreads();
  for (int cls = 0; cls < 10; cls++){
    float p = pooled[t] * pw[cls * 512 + t] + pooled[t + 256] * pw[cls * 512 + t + 256];
    p += __shfl_xor(p, 1); p += __shfl_xor(p, 2); p += __shfl_xor(p, 4);
    p += __shfl_xor(p, 8); p += __shfl_xor(p, 16); p += __shfl_xor(p, 32);
    if (lane == 0) red[w] = p;
    __syncthreads();
    if (t == 0) out[b * 10 + cls] = red[0] + red[1] + red[2] + red[3] + pb[cls];
    __syncthreads();
  }
}

extern "C" void kernel_launch(void* const* d_in, const int* in_sizes, int n_in,
                              void* d_out, int out_size, void* d_ws, size_t ws_size,
                              hipStream_t stream)
{
  const float* x      = (const float*)d_in[0];
  const float* lin_w  = (const float*)d_in[1];
  const float* lin_b  = (const float*)d_in[2];
  const float* qkvw_f = (const float*)d_in[3];
  const float* outw_f = (const float*)d_in[4];
  const float* lng    = (const float*)d_in[5];
  const float* lnb    = (const float*)d_in[6];
  const float* w1_f   = (const float*)d_in[7];
  const float* w2_f   = (const float*)d_in[8];
  const float* projw  = (const float*)d_in[9];
  const float* projb  = (const float*)d_in[10];
  float* out = (float*)d_out;

  char* ws = (char*)d_ws;
  float* hf32 = (float*)(ws);                    // 32768*512*4  = 64 MiB
  short* abuf = (short*)(ws + 67108864);         // 32768*512*2  = 32 MiB
  short* qkvb = (short*)(ws + 100663296);        // 32768*1536*2 = 96 MiB (shared with gbuf)
  short* gbuf = qkvb;                            // 32768*1408*2 = 88 MiB
  short* obuf = (short*)(ws + 201326592);        // 32 MiB
  float* part = (float*)(ws + 234881024);        // 8*32*512*4
  short* wqkv = (short*)(ws + 235405312);        // 4*1536*512*2
  short* wout = (short*)(ws + 247988224);        // 4*512*512*2
  short* w1p  = (short*)(ws + 250085376);        // 4*2816*512*2
  short* w2p  = (short*)(ws + 261619712);        // 4*512*1408*2 (end 267386880)

  cast_bf16_kernel<<<12288, 256, 0, stream>>>(qkvw_f, wqkv, 4 * 1536 * 512);
  cast_bf16_kernel<<<4096, 256, 0, stream>>>(outw_f, wout, 4 * 512 * 512);
  w1p_kernel<<<22528, 256, 0, stream>>>(w1_f, w1p);
  w2p_kernel<<<11264, 256, 0, stream>>>(w2_f, w2p);
  embed_kernel<<<65536, 256, 0, stream>>>(x, lin_w, lin_b, hf32, abuf);

  for (int l = 0; l < 4; l++){
    gemm_bt<0><<<dim3(12, 256), 256, 0, stream>>>(abuf, wqkv + (size_t)l * 1536 * 512, 512,
                                                  nullptr, qkvb, 1536);
    attn_kernel<<<dim3(32, 8, 8), 256, 0, stream>>>(qkvb, obuf);
    gemm_bt<1><<<dim3(4, 256), 256, 0, stream>>>(obuf, wout + (size_t)l * 512 * 512, 512,
                                                 hf32, nullptr, 0);
    ln_kernel<<<8192, 256, 0, stream>>>(hf32, lng + l * 512, lnb + l * 512, abuf);
    gemm_bt<3><<<dim3(22, 256), 256, 0, stream>>>(abuf, w1p + (size_t)l * 2816 * 512, 512,
                                                  nullptr, gbuf, 1408);
    gemm_bt<2><<<dim3(4, 256), 256, 0, stream>>>(gbuf, w2p + (size_t)l * 512 * 1408, 1408,
                                                 hf32, abuf, 512);
  }
  pool_partial<<<dim3(8, 32), 256, 0, stream>>>(hf32, part);
  pool_proj<<<8, 256, 0, stream>>>(part, projw, projb, out);
}

// Round 2
// 1830.331 us; speedup vs baseline: 1.0468x; 1.0468x over previous
//
#include <hip/hip_runtime.h>
#include <hip/hip_bf16.h>
#include <math.h>

typedef __attribute__((ext_vector_type(8))) short short8;
typedef __attribute__((ext_vector_type(4))) float f32x4;

__device__ __forceinline__ short f2bf(float f){
  unsigned u = __float_as_uint(f);
  u = (u + 0x7FFFu + ((u >> 16) & 1u)) >> 16;
  return (short)u;
}

// ---------------- weight prep ----------------
__global__ void cast_bf16_kernel(const float* __restrict__ s, short* __restrict__ d, int n){
  int i = blockIdx.x * 256 + threadIdx.x;
  if (i < n) d[i] = f2bf(s[i]);
}

// ff_w1 (4,2730,512) -> W1p (4,2816,512), rows interleaved: 2j <- u_j (row j), 2j+1 <- gate_j (row 1365+j)
__global__ void w1p_kernel(const float* __restrict__ s, short* __restrict__ d){
  int i = blockIdx.x * 256 + threadIdx.x;   // 4*2816*512
  int c  = i & 511;
  int rl = i >> 9;
  int r  = rl % 2816;
  int l  = rl / 2816;
  float v = 0.f;
  if (r < 2730){
    int sr = (r & 1) ? (1365 + (r >> 1)) : (r >> 1);
    v = s[((size_t)l * 2730 + sr) * 512 + c];
  }
  d[i] = f2bf(v);
}

// ff_w2 (4,512,1365) -> W2p (4,512,1408), K zero-padded
__global__ void w2p_kernel(const float* __restrict__ s, short* __restrict__ d){
  int i = blockIdx.x * 256 + threadIdx.x;   // 4*512*1408
  int c = i % 1408;
  int r = i / 1408;                          // l*512 + row
  float v = (c < 1365) ? s[(size_t)r * 1365 + c] : 0.f;
  d[i] = f2bf(v);
}

// ---------------- embedding ----------------
__global__ void embed_kernel(const float* __restrict__ x, const float* __restrict__ w,
                             const float* __restrict__ bias, float* __restrict__ hf,
                             short* __restrict__ hb){
  long i = (long)blockIdx.x * 256 + threadIdx.x;  // 32768*512
  long row = i >> 9; int e = (int)(i & 511);
  float v = x[row] * w[e] + bias[e];
  hf[i] = v;
  hb[i] = f2bf(v);
}

// ---------------- GEMM: C = A(MxK bf16) * B(NxK bf16)^T ----------------
// Staging: global_load_lds width=16, LDS linear, swizzle applied on the GLOBAL
// source column (rule #21): LDS[row][c16] = G[row][c16 ^ (row&7)].
// Read side uses the same involution: G[r][c] is at LDS byte (r*128+c*16)^((r&7)<<4).
// EPI: 0 = store bf16 to Cbf(ldcb); 1 = Cres(512) += acc (f32);
//      2 = Cres += acc, also store bf16 to Cbf(512); 3 = GEGLU pairs -> Cbf(ldcb)
template<int EPI>
__global__ __launch_bounds__(256, 4)
void gemm_bt(const short* __restrict__ A, const short* __restrict__ B, int K,
             float* __restrict__ Cres, short* __restrict__ Cbf, int ldcb)
{
  __shared__ short As[128 * 64];
  __shared__ short Bs[128 * 64];
  const int tid  = threadIdx.x;
  const int lane = tid & 63;
  const int w    = tid >> 6;
  const int wr   = (w >> 1) * 64, wc = (w & 1) * 64;

  // XCD-aware tile swizzle: contiguous tile chunk per XCD (nwg % 8 == 0 for all grids)
  const int nwg = gridDim.x * gridDim.y;
  const int f   = blockIdx.y * gridDim.x + blockIdx.x;
  const int s   = (f & 7) * (nwg >> 3) + (f >> 3);
  const long tm = (long)(s / gridDim.x) * 128;
  const long tn = (long)(s % gridDim.x) * 128;

  f32x4 acc[4][4];
  #pragma unroll
  for (int i = 0; i < 4; i++)
    #pragma unroll
    for (int j = 0; j < 4; j++)
      acc[i][j] = (f32x4){0.f, 0.f, 0.f, 0.f};

  // staging: wave w stages LDS chunks q = w*4+c (1 KiB each, rows q*8..q*8+7).
  // lane -> row offset lane>>3, pre-swizzled src col16 = (lane&7)^(lane>>3)
  // (row&7 == lane>>3 since w*32+c*8 is a multiple of 8).
  const int srow = lane >> 3;
  const int scol = (lane & 7) ^ srow;
  const short* aSrc = A + (size_t)(tm + w * 32 + srow) * K + scol * 8;
  const short* bSrc = B + (size_t)(tn + w * 32 + srow) * K + scol * 8;
  short* aDst = As + w * 2048;   // (w*4)*512 shorts = w*4 KiB
  short* bDst = Bs + w * 2048;

  for (int k0 = 0; k0 < K; k0 += 64){
    __syncthreads();
    #pragma unroll
    for (int c = 0; c < 4; c++){
      __builtin_amdgcn_global_load_lds(
        (const __attribute__((address_space(1))) void*)(aSrc + (size_t)c * 8 * K + k0),
        (__attribute__((address_space(3))) void*)(aDst + c * 512), 16, 0, 0);
      __builtin_amdgcn_global_load_lds(
        (const __attribute__((address_space(1))) void*)(bSrc + (size_t)c * 8 * K + k0),
        (__attribute__((address_space(3))) void*)(bDst + c * 512), 16, 0, 0);
    }
    __syncthreads();
    #pragma unroll
    for (int kk = 0; kk < 2; kk++){
      short8 a[4], b[4];
      int ac = (kk * 32 + (lane >> 4) * 8) * 2;
      #pragma unroll
      for (int i = 0; i < 4; i++){
        int ar = wr + i * 16 + (lane & 15);
        a[i] = *(const short8*)((char*)As + ((ar * 128 + ac) ^ ((ar & 7) << 4)));
        int br = wc + i * 16 + (lane & 15);
        b[i] = *(const short8*)((char*)Bs + ((br * 128 + ac) ^ ((br & 7) << 4)));
      }
      #pragma unroll
      for (int i = 0; i < 4; i++)
        #pragma unroll
        for (int j = 0; j < 4; j++)
          acc[i][j] = __builtin_amdgcn_mfma_f32_16x16x32_bf16(a[i], b[j], acc[i][j], 0, 0, 0);
    }
  }

  #pragma unroll
  for (int i = 0; i < 4; i++){
    #pragma unroll
    for (int j = 0; j < 4; j++){
      #pragma unroll
      for (int v = 0; v < 4; v++){
        long row = tm + wr + i * 16 + (lane >> 4) * 4 + v;
        long col = tn + wc + j * 16 + (lane & 15);
        float x = acc[i][j][v];
        if (EPI == 0){
          Cbf[row * ldcb + col] = f2bf(x);
        } else if (EPI == 1){
          float rr = x + Cres[row * 512 + col];
          Cres[row * 512 + col] = rr;
        } else if (EPI == 2){
          float rr = x + Cres[row * 512 + col];
          Cres[row * 512 + col] = rr;
          Cbf[row * 512 + col] = f2bf(rr);
        } else {
          float other = __shfl_xor(x, 1);
          if ((lane & 1) == 0){
            float gate = other;
            float gg = 0.5f * gate * (1.f + erff(gate * 0.70710678118f));
            Cbf[row * ldcb + (col >> 1)] = f2bf(x * gg);
          }
        }
      }
    }
  }
}

// ---------------- local attention ----------------
// grid (32 windows, 8 heads, 8 batch), 256 threads (4 waves x 32 q-rows)
__global__ __launch_bounds__(256, 2)
void attn_kernel(const short* __restrict__ qkv, short* __restrict__ o)
{
  __shared__ short Ks[128 * 64];     // swizzled [key][d]
  __shared__ short Vt[64 * 136];     // [d][key], stride 136
  __shared__ short Ps[4 * 32 * 128]; // per-wave swizzled P
  const int win = blockIdx.x, hh = blockIdx.y, b = blockIdx.z;
  const int tid = threadIdx.x, lane = tid & 63, w = tid >> 6;
  const long qrow0 = (long)b * 4096 + (long)win * 128;

  // Q fragments straight from global (A-operand layout == 8 contiguous d per lane)
  short8 qf[2][2];
  #pragma unroll
  for (int i = 0; i < 2; i++)
    #pragma unroll
    for (int kk = 0; kk < 2; kk++)
      qf[i][kk] = *(const short8*)(qkv + (qrow0 + w * 32 + i * 16 + (lane & 15)) * 1536
                                   + hh * 64 + kk * 32 + (lane >> 4) * 8);

  f32x4 oacc[2][4];
  #pragma unroll
  for (int i = 0; i < 2; i++)
    #pragma unroll
    for (int j = 0; j < 4; j++)
      oacc[i][j] = (f32x4){0.f, 0.f, 0.f, 0.f};
  float rs[2][4];
  #pragma unroll
  for (int i = 0; i < 2; i++)
    #pragma unroll
    for (int v = 0; v < 4; v++)
      rs[i][v] = 0.f;

  const int row_s = tid >> 3, c_s = tid & 7;
  for (int cc = 0; cc < 3; cc++){
    int kw = win - 1 + cc;
    if (kw < 0 || kw >= 32) continue;     // uniform per block
    const long krow0 = (long)b * 4096 + (long)kw * 128;
    __syncthreads();
    #pragma unroll
    for (int r = 0; r < 4; r++){
      int row = row_s + r * 32;
      const short* src = qkv + (krow0 + row) * 1536 + hh * 64;
      short8 kv = *(const short8*)(src + 512 + c_s * 8);
      *(short8*)((char*)Ks + ((row * 128 + c_s * 16) ^ ((row & 7) << 4))) = kv;
      short8 vv = *(const short8*)(src + 1024 + c_s * 8);
      #pragma unroll
      for (int e = 0; e < 8; e++) Vt[(c_s * 8 + e) * 136 + row] = vv[e];
    }
    __syncthreads();

    // QK^T
    f32x4 sacc[2][8];
    #pragma unroll
    for (int i = 0; i < 2; i++)
      #pragma unroll
      for (int j = 0; j < 8; j++)
        sacc[i][j] = (f32x4){0.f, 0.f, 0.f, 0.f};
    #pragma unroll
    for (int kk = 0; kk < 2; kk++){
      short8 bb[8];
      int ac = (kk * 32 + (lane >> 4) * 8) * 2;
      #pragma unroll
      for (int j = 0; j < 8; j++){
        int br = j * 16 + (lane & 15);
        bb[j] = *(const short8*)((char*)Ks + ((br * 128 + ac) ^ ((br & 7) << 4)));
      }
      #pragma unroll
      for (int i = 0; i < 2; i++)
        #pragma unroll
        for (int j = 0; j < 8; j++)
          sacc[i][j] = __builtin_amdgcn_mfma_f32_16x16x32_bf16(qf[i][kk], bb[j], sacc[i][j], 0, 0, 0);
    }

    // P = exp(s/8), row sums, transpose P through per-wave LDS
    short* myPs = Ps + w * 32 * 128;
    float psum[2][4];
    #pragma unroll
    for (int i = 0; i < 2; i++)
      #pragma unroll
      for (int v = 0; v < 4; v++)
        psum[i][v] = 0.f;
    #pragma unroll
    for (int i = 0; i < 2; i++)
      #pragma unroll
      for (int j = 0; j < 8; j++)
        #pragma unroll
        for (int v = 0; v < 4; v++){
          float p = expf(0.125f * sacc[i][j][v]);
          psum[i][v] += p;
          int prow = i * 16 + (lane >> 4) * 4 + v;
          int pcb  = (j * 16 + (lane & 15)) * 2;
          *(short*)((char*)myPs + ((prow * 256 + pcb) ^ ((prow & 7) << 4))) = f2bf(p);
        }
    #pragma unroll
    for (int i = 0; i < 2; i++)
      #pragma unroll
      for (int v = 0; v < 4; v++){
        float s = psum[i][v];
        s += __shfl_xor(s, 1); s += __shfl_xor(s, 2);
        s += __shfl_xor(s, 4); s += __shfl_xor(s, 8);
        rs[i][v] += s;
      }
    __syncthreads();

    // PV
    #pragma unroll
    for (int kk = 0; kk < 4; kk++){
      short8 pa[2], vb[4];
      int kb = (kk * 32 + (lane >> 4) * 8) * 2;
      #pragma unroll
      for (int i = 0; i < 2; i++){
        int pr = i * 16 + (lane & 15);
        pa[i] = *(const short8*)((char*)myPs + ((pr * 256 + kb) ^ ((pr & 7) << 4)));
      }
      #pragma unroll
      for (int j = 0; j < 4; j++){
        int vr = j * 16 + (lane & 15);
        vb[j] = *(const short8*)((char*)Vt + (vr * 272 + kb));
      }
      #pragma unroll
      for (int i = 0; i < 2; i++)
        #pragma unroll
        for (int j = 0; j < 4; j++)
          oacc[i][j] = __builtin_amdgcn_mfma_f32_16x16x32_bf16(pa[i], vb[j], oacc[i][j], 0, 0, 0);
    }
  }

  #pragma unroll
  for (int i = 0; i < 2; i++)
    #pragma unroll
    for (int j = 0; j < 4; j++)
      #pragma unroll
      for (int v = 0; v < 4; v++){
        long row = qrow0 + w * 32 + i * 16 + (lane >> 4) * 4 + v;
        int col = hh * 64 + j * 16 + (lane & 15);
        o[row * 512 + col] = f2bf(oacc[i][j][v] / rs[i][v]);
      }
}

// ---------------- layernorm (one wave per row) ----------------
__global__ __launch_bounds__(256)
void ln_kernel(const float* __restrict__ h, const float* __restrict__ g,
               const float* __restrict__ be, short* __restrict__ y)
{
  long row = (long)blockIdx.x * 4 + (threadIdx.x >> 6);
  int lane = threadIdx.x & 63;
  const float* x = h + row * 512 + lane * 8;
  float4 a0 = *(const float4*)x;
  float4 a1 = *(const float4*)(x + 4);
  float v[8] = {a0.x, a0.y, a0.z, a0.w, a1.x, a1.y, a1.z, a1.w};
  float s = 0.f, sq = 0.f;
  #pragma unroll
  for (int j = 0; j < 8; j++){ s += v[j]; sq += v[j] * v[j]; }
  #pragma unroll
  for (int m = 1; m <= 32; m <<= 1){ s += __shfl_xor(s, m); sq += __shfl_xor(sq, m); }
  float mu = s * (1.f / 512.f);
  float var = sq * (1.f / 512.f) - mu * mu;
  float rstd = rsqrtf(var + 1e-5f);
  short* yo = y + row * 512 + lane * 8;
  #pragma unroll
  for (int j = 0; j < 8; j++){
    int c = lane * 8 + j;
    yo[j] = f2bf((v[j] - mu) * rstd * g[c] + be[c]);
  }
}

// ---------------- mean pool + classifier ----------------
__global__ void pool_partial(const float* __restrict__ h, float* __restrict__ part){
  int b = blockIdx.x, ch = blockIdx.y, t = threadIdx.x;
  float s0 = 0.f, s1 = 0.f;
  const float* base = h + ((long)b * 4096 + ch * 128) * 512;
  for (int n = 0; n < 128; n++){
    s0 += base[(long)n * 512 + t];
    s1 += base[(long)n * 512 + t + 256];
  }
  part[((b * 32 + ch) * 512) + t] = s0;
  part[((b * 32 + ch) * 512) + t + 256] = s1;
}

__global__ void pool_proj(const float* __restrict__ part, const float* __restrict__ pw,
                          const float* __restrict__ pb, float* __restrict__ out){
  __shared__ float pooled[512];
  __shared__ float red[4];
  int b = blockIdx.x, t = threadIdx.x;
  int lane = t & 63, w = t >> 6;
  float s0 = 0.f, s1 = 0.f;
  for (int ch = 0; ch < 32; ch++){
    s0 += part[((b * 32 + ch) * 512) + t];
    s1 += part[((b * 32 + ch) * 512) + t + 256];
  }
  pooled[t] = s0 * (1.f / 4096.f);
  pooled[t + 256] = s1 * (1.f / 4096.f);
  __syncthreads();
  for (int cls = 0; cls < 10; cls++){
    float p = pooled[t] * pw[cls * 512 + t] + pooled[t + 256] * pw[cls * 512 + t + 256];
    p += __shfl_xor(p, 1); p += __shfl_xor(p, 2); p += __shfl_xor(p, 4);
    p += __shfl_xor(p, 8); p += __shfl_xor(p, 16); p += __shfl_xor(p, 32);
    if (lane == 0) red[w] = p;
    __syncthreads();
    if (t == 0) out[b * 10 + cls] = red[0] + red[1] + red[2] + red[3] + pb[cls];
    __syncthreads();
  }
}

extern "C" void kernel_launch(void* const* d_in, const int* in_sizes, int n_in,
                              void* d_out, int out_size, void* d_ws, size_t ws_size,
                              hipStream_t stream)
{
  const float* x      = (const float*)d_in[0];
  const float* lin_w  = (const float*)d_in[1];
  const float* lin_b  = (const float*)d_in[2];
  const float* qkvw_f = (const float*)d_in[3];
  const float* outw_f = (const float*)d_in[4];
  const float* lng    = (const float*)d_in[5];
  const float* lnb    = (const float*)d_in[6];
  const float* w1_f   = (const float*)d_in[7];
  const float* w2_f   = (const float*)d_in[8];
  const float* projw  = (const float*)d_in[9];
  const float* projb  = (const float*)d_in[10];
  float* out = (float*)d_out;

  char* ws = (char*)d_ws;
  float* hf32 = (float*)(ws);                    // 32768*512*4  = 64 MiB
  short* abuf = (short*)(ws + 67108864);         // 32768*512*2  = 32 MiB
  short* qkvb = (short*)(ws + 100663296);        // 32768*1536*2 = 96 MiB (shared with gbuf)
  short* gbuf = qkvb;                            // 32768*1408*2 = 88 MiB
  short* obuf = (short*)(ws + 201326592);        // 32 MiB
  float* part = (float*)(ws + 234881024);        // 8*32*512*4
  short* wqkv = (short*)(ws + 235405312);        // 4*1536*512*2
  short* wout = (short*)(ws + 247988224);        // 4*512*512*2
  short* w1p  = (short*)(ws + 250085376);        // 4*2816*512*2
  short* w2p  = (short*)(ws + 261619712);        // 4*512*1408*2 (end 267386880)

  cast_bf16_kernel<<<12288, 256, 0, stream>>>(qkvw_f, wqkv, 4 * 1536 * 512);
  cast_bf16_kernel<<<4096, 256, 0, stream>>>(outw_f, wout, 4 * 512 * 512);
  w1p_kernel<<<22528, 256, 0, stream>>>(w1_f, w1p);
  w2p_kernel<<<11264, 256, 0, stream>>>(w2_f, w2p);
  embed_kernel<<<65536, 256, 0, stream>>>(x, lin_w, lin_b, hf32, abuf);

  for (int l = 0; l < 4; l++){
    gemm_bt<0><<<dim3(12, 256), 256, 0, stream>>>(abuf, wqkv + (size_t)l * 1536 * 512, 512,
                                                  nullptr, qkvb, 1536);
    attn_kernel<<<dim3(32, 8, 8), 256, 0, stream>>>(qkvb, obuf);
    gemm_bt<1><<<dim3(4, 256), 256, 0, stream>>>(obuf, wout + (size_t)l * 512 * 512, 512,
                                                 hf32, nullptr, 0);
    ln_kernel<<<8192, 256, 0, stream>>>(hf32, lng + l * 512, lnb + l * 512, abuf);
    gemm_bt<3><<<dim3(22, 256), 256, 0, stream>>>(abuf, w1p + (size_t)l * 2816 * 512, 512,
                                                  nullptr, gbuf, 1408);
    gemm_bt<2><<<dim3(4, 256), 256, 0, stream>>>(gbuf, w2p + (size_t)l * 512 * 1408, 1408,
                                                 hf32, abuf, 512);
  }
  pool_partial<<<dim3(8, 32), 256, 0, stream>>>(hf32, part);
  pool_proj<<<8, 256, 0, stream>>>(part, projw, projb, out);
}

// Round 3
// 1822.636 us; speedup vs baseline: 1.0512x; 1.0042x over previous
//
#include <hip/hip_runtime.h>
#include <hip/hip_bf16.h>
#include <math.h>

typedef __attribute__((ext_vector_type(8))) short short8;
typedef __attribute__((ext_vector_type(4))) float f32x4;

#define MFMA16 __builtin_amdgcn_mfma_f32_16x16x32_bf16

__device__ __forceinline__ short f2bf(float f){
  unsigned u = __float_as_uint(f);
  u = (u + 0x7FFFu + ((u >> 16) & 1u)) >> 16;
  return (short)u;
}

// exact-enough erf-based gelu factor Phi(g)=0.5*(1+erf(g/sqrt2)); |erf err|<=1.5e-7 (A&S 7.1.26)
__device__ __forceinline__ float gelu_phi(float g){
  float ax = fabsf(g) * 0.70710678118f;
  float t  = 1.f / (1.f + 0.3275911f * ax);
  float pp = ((((1.061405429f * t - 1.453152027f) * t + 1.421413741f) * t
               - 0.284496736f) * t + 0.254829592f) * t;
  float e  = 1.f - pp * __expf(-ax * ax);
  return 0.5f + copysignf(0.5f, g) * e;
}

// ---------------- weight prep ----------------
__global__ void cast_bf16_kernel(const float* __restrict__ s, short* __restrict__ d, int n){
  int i = blockIdx.x * 256 + threadIdx.x;
  if (i < n) d[i] = f2bf(s[i]);
}

// ff_w1 (4,2730,512) -> W1p (4,2816,512). 32-row groups: rows g*32+s:
// s<16 -> u_j, s>=16 -> gate_j, j = g*16 + (s&15); zero-pad j>=1365.
// So C fragments pair: ni even = u, ni odd = gate for identical output cols.
__global__ void w1p_kernel(const float* __restrict__ s, short* __restrict__ d){
  int i = blockIdx.x * 256 + threadIdx.x;   // 4*2816*512
  int c  = i & 511;
  int rl = i >> 9;
  int r  = rl % 2816;
  int l  = rl / 2816;
  int g  = r >> 5, sfx = r & 31;
  int j  = g * 16 + (sfx & 15);
  float v = 0.f;
  if (j < 1365){
    int sr = (sfx < 16) ? j : 1365 + j;
    v = s[((size_t)l * 2730 + sr) * 512 + c];
  }
  d[i] = f2bf(v);
}

// ff_w2 (4,512,1365) -> W2p (4,512,1408), K zero-padded
__global__ void w2p_kernel(const float* __restrict__ s, short* __restrict__ d){
  int i = blockIdx.x * 256 + threadIdx.x;   // 4*512*1408
  int c = i % 1408;
  int r = i / 1408;
  float v = (c < 1365) ? s[(size_t)r * 1365 + c] : 0.f;
  d[i] = f2bf(v);
}

// ---------------- embedding ----------------
__global__ void embed_kernel(const float* __restrict__ x, const float* __restrict__ w,
                             const float* __restrict__ bias, float* __restrict__ hf,
                             short* __restrict__ hb){
  long i = (long)blockIdx.x * 256 + threadIdx.x;  // 32768*512
  long row = i >> 9; int e = (int)(i & 511);
  float v = x[row] * w[e] + bias[e];
  hf[i] = v;
  hb[i] = f2bf(v);
}

// ---------------- 256x256 8-phase GEMM: C = A(MxK bf16) * B(NxK bf16)^T ----------------
// 8 waves (2M x 4N), BK=64, double-buffered 128KiB LDS, T2 swizzle via pre-swizzled
// global source (gload_lds writes linear), counted vmcnt(6) once per K-tile (T4),
// setprio around MFMA clusters (T5), XCD-aware tile swizzle (T1).
// EPI: 0 = bf16 store (ldcb); 1 = Cres += acc; 2 = Cres += acc & bf16 store; 3 = GEGLU.
template<int EPI>
__global__ __launch_bounds__(512, 2)
void gemm256(const short* __restrict__ A, const short* __restrict__ B, int K,
             float* __restrict__ Cres, short* __restrict__ Cbf, int ldcb)
{
  __shared__ short As[2][256][64];   // 64 KiB
  __shared__ short Bs[2][256][64];   // 64 KiB
  char* smA = (char*)As;
  char* smB = (char*)Bs;

  const int tid  = threadIdx.x;
  const int lane = tid & 63;
  const int w    = tid >> 6;
  const int wm   = w >> 2;           // 0..1
  const int wn   = w & 3;            // 0..3
  const int NT   = K >> 6;

  // T1: XCD-aware tile swizzle (all grids have nwg % 8 == 0)
  const int nwg = gridDim.x * gridDim.y;
  const int f   = blockIdx.y * gridDim.x + blockIdx.x;
  const int sw  = (f & 7) * (nwg >> 3) + (f >> 3);
  const long tm = (long)(sw / gridDim.x) * 256;
  const long tn = (long)(sw % gridDim.x) * 256;

  // staging: thread covers chunk q=tid (rows 0-63 of a 128-row half) and q=tid+512 (rows 64-127)
  const int r0 = tid >> 3;                 // row within half, 0..63
  const int c0 = (tid & 7) ^ (r0 & 7);     // pre-swizzled source chunk (T2 both-sides)
  const short* aS = A + (tm + r0) * (long)K + c0 * 8;
  const short* bS = B + (tn + r0) * (long)K + c0 * 8;
  const int ldsW0 = w * 1024;              // wave-uniform LDS dest base, lane*16 appended by HW
  const int ldsW1 = 8192 + w * 1024;
  const long halfA = 128 * (long)K;

  auto stgA = [&](int dstoff, const short* srcp){
    __builtin_amdgcn_global_load_lds((const __attribute__((address_space(1))) void*)(srcp),
        (__attribute__((address_space(3))) void*)(smA + dstoff + ldsW0), 16, 0, 0);
    __builtin_amdgcn_global_load_lds((const __attribute__((address_space(1))) void*)(srcp + 64 * (long)K),
        (__attribute__((address_space(3))) void*)(smA + dstoff + ldsW1), 16, 0, 0);
  };
  auto stgB = [&](int dstoff, const short* srcp){
    __builtin_amdgcn_global_load_lds((const __attribute__((address_space(1))) void*)(srcp),
        (__attribute__((address_space(3))) void*)(smB + dstoff + ldsW0), 16, 0, 0);
    __builtin_amdgcn_global_load_lds((const __attribute__((address_space(1))) void*)(srcp + 64 * (long)K),
        (__attribute__((address_space(3))) void*)(smB + dstoff + ldsW1), 16, 0, 0);
  };

  f32x4 acc[8][4];
  #pragma unroll
  for (int i = 0; i < 8; i++)
    #pragma unroll
    for (int j = 0; j < 4; j++)
      acc[i][j] = (f32x4){0.f, 0.f, 0.f, 0.f};

  // fragment read addressing (read-side swizzle: same involution as source pre-swizzle)
  const int rb  = (lane & 15) * 128;
  const int ct0 = (((lane >> 4)    ) ^ (lane & 7)) * 16;
  const int ct1 = ((4 + (lane >> 4)) ^ (lane & 7)) * 16;

  // ---- prologue: tile0 fully + tile1 {B0,A0,A1}; vmcnt(6) -> tile0 landed ----
  stgB(0,             bS);                  // (0,B0)
  stgA(0,             aS);                  // (0,A0)
  stgA(16384,         aS + halfA);          // (0,A1)
  stgB(16384,         bS + halfA);          // (0,B1)
  if (NT > 1){
    stgB(32768,         bS + 64);           // (1,B0)
    stgA(32768,         aS + 64);           // (1,A0)
    stgA(32768 + 16384, aS + halfA + 64);   // (1,A1)
  }
  asm volatile("s_waitcnt vmcnt(6)" ::: "memory");
  __builtin_amdgcn_s_barrier();

  for (int t = 0; t < NT; ++t){
    const int cur = (t & 1) * 32768;
    const int nxt = 32768 - cur;
    const bool s1 = (t + 1 < NT), s2 = (t + 2 < NT);
    const long o1 = (long)(t + 1) * 64, o2 = (long)(t + 2) * 64;
    short8 a0[8], a1[8], bb[4][2];

    // ---- phase 1: read all B + A(kk0); stage (t+1,B1); MFMA ni0-1 kk0 ----
    #pragma unroll
    for (int ni = 0; ni < 4; ni++){
      bb[ni][0] = *(const short8*)(smB + cur + wn * 8192 + ni * 2048 + rb + ct0);
      bb[ni][1] = *(const short8*)(smB + cur + wn * 8192 + ni * 2048 + rb + ct1);
    }
    #pragma unroll
    for (int mi = 0; mi < 8; mi++)
      a0[mi] = *(const short8*)(smA + cur + wm * 16384 + mi * 2048 + rb + ct0);
    if (s1) stgB(nxt + 16384, bS + halfA + o1);
    asm volatile("s_waitcnt lgkmcnt(0)" ::: "memory");
    __builtin_amdgcn_sched_barrier(0);
    __builtin_amdgcn_s_barrier();
    __builtin_amdgcn_s_setprio(1);
    #pragma unroll
    for (int mi = 0; mi < 8; mi++){
      acc[mi][0] = MFMA16(a0[mi], bb[0][0], acc[mi][0], 0, 0, 0);
      acc[mi][1] = MFMA16(a0[mi], bb[1][0], acc[mi][1], 0, 0, 0);
    }
    __builtin_amdgcn_s_setprio(0);
    __builtin_amdgcn_s_barrier();

    // ---- phase 2: read A(kk1); stage (t+2,B0); MFMA ni2-3 kk0 ----
    #pragma unroll
    for (int mi = 0; mi < 8; mi++)
      a1[mi] = *(const short8*)(smA + cur + wm * 16384 + mi * 2048 + rb + ct1);
    if (s2) stgB(cur, bS + o2);
    asm volatile("s_waitcnt lgkmcnt(0)" ::: "memory");
    __builtin_amdgcn_sched_barrier(0);
    __builtin_amdgcn_s_barrier();
    __builtin_amdgcn_s_setprio(1);
    #pragma unroll
    for (int mi = 0; mi < 8; mi++){
      acc[mi][2] = MFMA16(a0[mi], bb[2][0], acc[mi][2], 0, 0, 0);
      acc[mi][3] = MFMA16(a0[mi], bb[3][0], acc[mi][3], 0, 0, 0);
    }
    __builtin_amdgcn_s_setprio(0);
    __builtin_amdgcn_s_barrier();

    // ---- phase 3: stage (t+2,A0); MFMA ni0-1 kk1 ----
    if (s2) stgA(cur, aS + o2);
    __builtin_amdgcn_s_barrier();
    __builtin_amdgcn_s_setprio(1);
    #pragma unroll
    for (int mi = 0; mi < 8; mi++){
      acc[mi][0] = MFMA16(a1[mi], bb[0][1], acc[mi][0], 0, 0, 0);
      acc[mi][1] = MFMA16(a1[mi], bb[1][1], acc[mi][1], 0, 0, 0);
    }
    __builtin_amdgcn_s_setprio(0);
    __builtin_amdgcn_s_barrier();

    // ---- phase 4: stage (t+2,A1); counted vmcnt; MFMA ni2-3 kk1 ----
    if (s2) stgA(cur + 16384, aS + halfA + o2);
    if (t < NT - 2) asm volatile("s_waitcnt vmcnt(6)" ::: "memory");
    else            asm volatile("s_waitcnt vmcnt(0)" ::: "memory");
    __builtin_amdgcn_s_barrier();
    __builtin_amdgcn_s_setprio(1);
    #pragma unroll
    for (int mi = 0; mi < 8; mi++){
      acc[mi][2] = MFMA16(a1[mi], bb[2][1], acc[mi][2], 0, 0, 0);
      acc[mi][3] = MFMA16(a1[mi], bb[3][1], acc[mi][3], 0, 0, 0);
    }
    __builtin_amdgcn_s_setprio(0);
    __builtin_amdgcn_s_barrier();
  }

  // ---- epilogue ----
  #pragma unroll
  for (int mi = 0; mi < 8; mi++){
    if (EPI == 3){
      #pragma unroll
      for (int p = 0; p < 2; p++){
        #pragma unroll
        for (int v = 0; v < 4; v++){
          long row = tm + wm * 128 + mi * 16 + (lane >> 4) * 4 + v;
          long col = (tn >> 1) + wn * 32 + p * 16 + (lane & 15);
          float u = acc[mi][2 * p][v];
          float g = acc[mi][2 * p + 1][v];
          Cbf[row * ldcb + col] = f2bf(u * g * gelu_phi(g));
        }
      }
    } else {
      #pragma unroll
      for (int ni = 0; ni < 4; ni++){
        #pragma unroll
        for (int v = 0; v < 4; v++){
          long row = tm + wm * 128 + mi * 16 + (lane >> 4) * 4 + v;
          long col = tn + wn * 64 + ni * 16 + (lane & 15);
          float x = acc[mi][ni][v];
          if (EPI == 0){
            Cbf[row * ldcb + col] = f2bf(x);
          } else if (EPI == 1){
            Cres[row * 512 + col] = x + Cres[row * 512 + col];
          } else {
            float rr = x + Cres[row * 512 + col];
            Cres[row * 512 + col] = rr;
            Cbf[row * 512 + col] = f2bf(rr);
          }
        }
      }
    }
  }
}

// ---------------- local attention ----------------
// grid (32 windows, 8 heads, 8 batch), 256 threads (4 waves x 32 q-rows)
__global__ __launch_bounds__(256, 2)
void attn_kernel(const short* __restrict__ qkv, short* __restrict__ o)
{
  __shared__ short Ks[128 * 64];     // swizzled [key][d]
  __shared__ short Vt[64 * 136];     // [d][key], stride 136
  __shared__ short Ps[4 * 32 * 128]; // per-wave swizzled P
  const int win = blockIdx.x, hh = blockIdx.y, b = blockIdx.z;
  const int tid = threadIdx.x, lane = tid & 63, w = tid >> 6;
  const long qrow0 = (long)b * 4096 + (long)win * 128;

  short8 qf[2][2];
  #pragma unroll
  for (int i = 0; i < 2; i++)
    #pragma unroll
    for (int kk = 0; kk < 2; kk++)
      qf[i][kk] = *(const short8*)(qkv + (qrow0 + w * 32 + i * 16 + (lane & 15)) * 1536
                                   + hh * 64 + kk * 32 + (lane >> 4) * 8);

  f32x4 oacc[2][4];
  #pragma unroll
  for (int i = 0; i < 2; i++)
    #pragma unroll
    for (int j = 0; j < 4; j++)
      oacc[i][j] = (f32x4){0.f, 0.f, 0.f, 0.f};
  float rs[2][4];
  #pragma unroll
  for (int i = 0; i < 2; i++)
    #pragma unroll
    for (int v = 0; v < 4; v++)
      rs[i][v] = 0.f;

  const int row_s = tid >> 3, c_s = tid & 7;
  for (int cc = 0; cc < 3; cc++){
    int kw = win - 1 + cc;
    if (kw < 0 || kw >= 32) continue;
    const long krow0 = (long)b * 4096 + (long)kw * 128;
    __syncthreads();
    #pragma unroll
    for (int r = 0; r < 4; r++){
      int row = row_s + r * 32;
      const short* src = qkv + (krow0 + row) * 1536 + hh * 64;
      short8 kv = *(const short8*)(src + 512 + c_s * 8);
      *(short8*)((char*)Ks + ((row * 128 + c_s * 16) ^ ((row & 7) << 4))) = kv;
      short8 vv = *(const short8*)(src + 1024 + c_s * 8);
      #pragma unroll
      for (int e = 0; e < 8; e++) Vt[(c_s * 8 + e) * 136 + row] = vv[e];
    }
    __syncthreads();

    f32x4 sacc[2][8];
    #pragma unroll
    for (int i = 0; i < 2; i++)
      #pragma unroll
      for (int j = 0; j < 8; j++)
        sacc[i][j] = (f32x4){0.f, 0.f, 0.f, 0.f};
    #pragma unroll
    for (int kk = 0; kk < 2; kk++){
      short8 bbk[8];
      int ac = (kk * 32 + (lane >> 4) * 8) * 2;
      #pragma unroll
      for (int j = 0; j < 8; j++){
        int br = j * 16 + (lane & 15);
        bbk[j] = *(const short8*)((char*)Ks + ((br * 128 + ac) ^ ((br & 7) << 4)));
      }
      #pragma unroll
      for (int i = 0; i < 2; i++)
        #pragma unroll
        for (int j = 0; j < 8; j++)
          sacc[i][j] = MFMA16(qf[i][kk], bbk[j], sacc[i][j], 0, 0, 0);
    }

    short* myPs = Ps + w * 32 * 128;
    float psum[2][4];
    #pragma unroll
    for (int i = 0; i < 2; i++)
      #pragma unroll
      for (int v = 0; v < 4; v++)
        psum[i][v] = 0.f;
    #pragma unroll
    for (int i = 0; i < 2; i++)
      #pragma unroll
      for (int j = 0; j < 8; j++)
        #pragma unroll
        for (int v = 0; v < 4; v++){
          float p = expf(0.125f * sacc[i][j][v]);
          psum[i][v] += p;
          int prow = i * 16 + (lane >> 4) * 4 + v;
          int pcb  = (j * 16 + (lane & 15)) * 2;
          *(short*)((char*)myPs + ((prow * 256 + pcb) ^ ((prow & 7) << 4))) = f2bf(p);
        }
    #pragma unroll
    for (int i = 0; i < 2; i++)
      #pragma unroll
      for (int v = 0; v < 4; v++){
        float s = psum[i][v];
        s += __shfl_xor(s, 1); s += __shfl_xor(s, 2);
        s += __shfl_xor(s, 4); s += __shfl_xor(s, 8);
        rs[i][v] += s;
      }
    __syncthreads();

    #pragma unroll
    for (int kk = 0; kk < 4; kk++){
      short8 pa[2], vb[4];
      int kb = (kk * 32 + (lane >> 4) * 8) * 2;
      #pragma unroll
      for (int i = 0; i < 2; i++){
        int pr = i * 16 + (lane & 15);
        pa[i] = *(const short8*)((char*)myPs + ((pr * 256 + kb) ^ ((pr & 7) << 4)));
      }
      #pragma unroll
      for (int j = 0; j < 4; j++){
        int vr = j * 16 + (lane & 15);
        vb[j] = *(const short8*)((char*)Vt + (vr * 272 + kb));
      }
      #pragma unroll
      for (int i = 0; i < 2; i++)
        #pragma unroll
        for (int j = 0; j < 4; j++)
          oacc[i][j] = MFMA16(pa[i], vb[j], oacc[i][j], 0, 0, 0);
    }
  }

  #pragma unroll
  for (int i = 0; i < 2; i++)
    #pragma unroll
    for (int j = 0; j < 4; j++)
      #pragma unroll
      for (int v = 0; v < 4; v++){
        long row = qrow0 + w * 32 + i * 16 + (lane >> 4) * 4 + v;
        int col = hh * 64 + j * 16 + (lane & 15);
        o[row * 512 + col] = f2bf(oacc[i][j][v] / rs[i][v]);
      }
}

// ---------------- layernorm (one wave per row) ----------------
__global__ __launch_bounds__(256)
void ln_kernel(const float* __restrict__ h, const float* __restrict__ g,
               const float* __restrict__ be, short* __restrict__ y)
{
  long row = (long)blockIdx.x * 4 + (threadIdx.x >> 6);
  int lane = threadIdx.x & 63;
  const float* x = h + row * 512 + lane * 8;
  float4 a0 = *(const float4*)x;
  float4 a1 = *(const float4*)(x + 4);
  float v[8] = {a0.x, a0.y, a0.z, a0.w, a1.x, a1.y, a1.z, a1.w};
  float s = 0.f, sq = 0.f;
  #pragma unroll
  for (int j = 0; j < 8; j++){ s += v[j]; sq += v[j] * v[j]; }
  #pragma unroll
  for (int m = 1; m <= 32; m <<= 1){ s += __shfl_xor(s, m); sq += __shfl_xor(sq, m); }
  float mu = s * (1.f / 512.f);
  float var = sq * (1.f / 512.f) - mu * mu;
  float rstd = rsqrtf(var + 1e-5f);
  short* yo = y + row * 512 + lane * 8;
  #pragma unroll
  for (int j = 0; j < 8; j++){
    int c = lane * 8 + j;
    yo[j] = f2bf((v[j] - mu) * rstd * g[c] + be[c]);
  }
}

// ---------------- mean pool + classifier ----------------
__global__ void pool_partial(const float* __restrict__ h, float* __restrict__ part){
  int b = blockIdx.x, ch = blockIdx.y, t = threadIdx.x;
  float s0 = 0.f, s1 = 0.f;
  const float* base = h + ((long)b * 4096 + ch * 128) * 512;
  for (int n = 0; n < 128; n++){
    s0 += base[(long)n * 512 + t];
    s1 += base[(long)n * 512 + t + 256];
  }
  part[((b * 32 + ch) * 512) + t] = s0;
  part[((b * 32 + ch) * 512) + t + 256] = s1;
}

__global__ void pool_proj(const float* __restrict__ part, const float* __restrict__ pw,
                          const float* __restrict__ pb, float* __restrict__ out){
  __shared__ float pooled[512];
  __shared__ float red[4];
  int b = blockIdx.x, t = threadIdx.x;
  int lane = t & 63, w = t >> 6;
  float s0 = 0.f, s1 = 0.f;
  for (int ch = 0; ch < 32; ch++){
    s0 += part[((b * 32 + ch) * 512) + t];
    s1 += part[((b * 32 + ch) * 512) + t + 256];
  }
  pooled[t] = s0 * (1.f / 4096.f);
  pooled[t + 256] = s1 * (1.f / 4096.f);
  __syncthreads();
  for (int cls = 0; cls < 10; cls++){
    float p = pooled[t] * pw[cls * 512 + t] + pooled[t + 256] * pw[cls * 512 + t + 256];
    p += __shfl_xor(p, 1); p += __shfl_xor(p, 2); p += __shfl_xor(p, 4);
    p += __shfl_xor(p, 8); p += __shfl_xor(p, 16); p += __shfl_xor(p, 32);
    if (lane == 0) red[w] = p;
    __syncthreads();
    if (t == 0) out[b * 10 + cls] = red[0] + red[1] + red[2] + red[3] + pb[cls];
    __syncthreads();
  }
}

extern "C" void kernel_launch(void* const* d_in, const int* in_sizes, int n_in,
                              void* d_out, int out_size, void* d_ws, size_t ws_size,
                              hipStream_t stream)
{
  const float* x      = (const float*)d_in[0];
  const float* lin_w  = (const float*)d_in[1];
  const float* lin_b  = (const float*)d_in[2];
  const float* qkvw_f = (const float*)d_in[3];
  const float* outw_f = (const float*)d_in[4];
  const float* lng    = (const float*)d_in[5];
  const float* lnb    = (const float*)d_in[6];
  const float* w1_f   = (const float*)d_in[7];
  const float* w2_f   = (const float*)d_in[8];
  const float* projw  = (const float*)d_in[9];
  const float* projb  = (const float*)d_in[10];
  float* out = (float*)d_out;

  char* ws = (char*)d_ws;
  float* hf32 = (float*)(ws);                    // 32768*512*4  = 64 MiB
  short* abuf = (short*)(ws + 67108864);         // 32768*512*2  = 32 MiB
  short* qkvb = (short*)(ws + 100663296);        // 32768*1536*2 = 96 MiB (shared with gbuf)
  short* gbuf = qkvb;                            // 32768*1408*2 = 88 MiB
  short* obuf = (short*)(ws + 201326592);        // 32 MiB
  float* part = (float*)(ws + 234881024);        // 8*32*512*4
  short* wqkv = (short*)(ws + 235405312);        // 4*1536*512*2
  short* wout = (short*)(ws + 247988224);        // 4*512*512*2
  short* w1p  = (short*)(ws + 250085376);        // 4*2816*512*2
  short* w2p  = (short*)(ws + 261619712);        // 4*512*1408*2 (end 267386880)

  cast_bf16_kernel<<<12288, 256, 0, stream>>>(qkvw_f, wqkv, 4 * 1536 * 512);
  cast_bf16_kernel<<<4096, 256, 0, stream>>>(outw_f, wout, 4 * 512 * 512);
  w1p_kernel<<<22528, 256, 0, stream>>>(w1_f, w1p);
  w2p_kernel<<<11264, 256, 0, stream>>>(w2_f, w2p);
  embed_kernel<<<65536, 256, 0, stream>>>(x, lin_w, lin_b, hf32, abuf);

  for (int l = 0; l < 4; l++){
    gemm256<0><<<dim3(6, 128), 512, 0, stream>>>(abuf, wqkv + (size_t)l * 1536 * 512, 512,
                                                 nullptr, qkvb, 1536);
    attn_kernel<<<dim3(32, 8, 8), 256, 0, stream>>>(qkvb, obuf);
    gemm256<1><<<dim3(2, 128), 512, 0, stream>>>(obuf, wout + (size_t)l * 512 * 512, 512,
                                                 hf32, nullptr, 0);
    ln_kernel<<<8192, 256, 0, stream>>>(hf32, lng + l * 512, lnb + l * 512, abuf);
    gemm256<3><<<dim3(11, 128), 512, 0, stream>>>(abuf, w1p + (size_t)l * 2816 * 512, 512,
                                                  nullptr, gbuf, 1408);
    gemm256<2><<<dim3(2, 128), 512, 0, stream>>>(gbuf, w2p + (size_t)l * 512 * 1408, 1408,
                                                 hf32, abuf, 512);
  }
  pool_partial<<<dim3(8, 32), 256, 0, stream>>>(hf32, part);
  pool_proj<<<8, 256, 0, stream>>>(part, projw, projb, out);
}

// Round 4
// 1815.456 us; speedup vs baseline: 1.0553x; 1.0040x over previous
//
#include <hip/hip_runtime.h>
#include <hip/hip_bf16.h>
#include <math.h>

typedef __attribute__((ext_vector_type(8))) short short8;
typedef __attribute__((ext_vector_type(4))) float f32x4;

#define MFMA16 __builtin_amdgcn_mfma_f32_16x16x32_bf16

__device__ __forceinline__ short f2bf(float f){
  unsigned u = __float_as_uint(f);
  u = (u + 0x7FFFu + ((u >> 16) & 1u)) >> 16;
  return (short)u;
}

// erf-based gelu factor Phi(g)=0.5*(1+erf(g/sqrt2)); |erf err|<=1.5e-7 (A&S 7.1.26)
__device__ __forceinline__ float gelu_phi(float g){
  float ax = fabsf(g) * 0.70710678118f;
  float t  = 1.f / (1.f + 0.3275911f * ax);
  float pp = ((((1.061405429f * t - 1.453152027f) * t + 1.421413741f) * t
               - 0.284496736f) * t + 0.254829592f) * t;
  float e  = 1.f - pp * __expf(-ax * ax);
  return 0.5f + copysignf(0.5f, g) * e;
}

// ---------------- weight prep ----------------
__global__ void cast_bf16_kernel(const float* __restrict__ s, short* __restrict__ d, int n){
  int i = blockIdx.x * 256 + threadIdx.x;
  if (i < n) d[i] = f2bf(s[i]);
}

// ff_w1 (4,2730,512) -> W1p (4,2816,512). 32-row groups: rows g*32+s:
// s<16 -> u_j, s>=16 -> gate_j, j = g*16 + (s&15); zero-pad j>=1365.
__global__ void w1p_kernel(const float* __restrict__ s, short* __restrict__ d){
  int i = blockIdx.x * 256 + threadIdx.x;   // 4*2816*512
  int c  = i & 511;
  int rl = i >> 9;
  int r  = rl % 2816;
  int l  = rl / 2816;
  int g  = r >> 5, sfx = r & 31;
  int j  = g * 16 + (sfx & 15);
  float v = 0.f;
  if (j < 1365){
    int sr = (sfx < 16) ? j : 1365 + j;
    v = s[((size_t)l * 2730 + sr) * 512 + c];
  }
  d[i] = f2bf(v);
}

// ff_w2 (4,512,1365) -> W2p (4,512,1408), K zero-padded
__global__ void w2p_kernel(const float* __restrict__ s, short* __restrict__ d){
  int i = blockIdx.x * 256 + threadIdx.x;   // 4*512*1408
  int c = i % 1408;
  int r = i / 1408;
  float v = (c < 1365) ? s[(size_t)r * 1365 + c] : 0.f;
  d[i] = f2bf(v);
}

// ---------------- embedding (x8 vectorized) ----------------
__global__ void embed_kernel(const float* __restrict__ x, const float* __restrict__ w,
                             const float* __restrict__ bias, float* __restrict__ hf,
                             short* __restrict__ hb){
  long i = ((long)blockIdx.x * 256 + threadIdx.x) * 8;  // 32768*512 total
  long row = i >> 9; int e = (int)(i & 511);
  float xv = x[row];
  float4 w0 = *(const float4*)(w + e),    w1 = *(const float4*)(w + e + 4);
  float4 b0 = *(const float4*)(bias + e), b1 = *(const float4*)(bias + e + 4);
  float4 o0, o1;
  o0.x = xv * w0.x + b0.x; o0.y = xv * w0.y + b0.y;
  o0.z = xv * w0.z + b0.z; o0.w = xv * w0.w + b0.w;
  o1.x = xv * w1.x + b1.x; o1.y = xv * w1.y + b1.y;
  o1.z = xv * w1.z + b1.z; o1.w = xv * w1.w + b1.w;
  *(float4*)(hf + i) = o0; *(float4*)(hf + i + 4) = o1;
  short8 hv;
  hv[0] = f2bf(o0.x); hv[1] = f2bf(o0.y); hv[2] = f2bf(o0.z); hv[3] = f2bf(o0.w);
  hv[4] = f2bf(o1.x); hv[5] = f2bf(o1.y); hv[6] = f2bf(o1.z); hv[7] = f2bf(o1.w);
  *(short8*)(hb + i) = hv;
}

// ---------------- 256x256 8-phase GEMM: C = A(MxK bf16) * B(NxK bf16)^T ----------------
// 8 waves (2M x 4N), BK=64, double-buffered 128KiB LDS. Per-phase register
// discipline: only a[4]+bb[4] fragments live (fits 256-reg budget, no spill).
// Stage rotation (race-audited): ph1 A0(t+1)->nxt, ph2 A1(t+1)->nxt,
// ph4 B0+B1(t+2)->cur (B-cur fully read by ph3-mid). vmcnt(4) once per K-tile.
// EPI: 0 = bf16 store (ldcb); 1 = Cres += acc; 2 = Cres += acc & bf16 store; 3 = GEGLU.
template<int EPI>
__global__ __launch_bounds__(512, 2)
void gemm256(const short* __restrict__ A, const short* __restrict__ B, int K,
             float* __restrict__ Cres, short* __restrict__ Cbf, int ldcb)
{
  __shared__ short As[2][256][64];   // 64 KiB
  __shared__ short Bs[2][256][64];   // 64 KiB
  char* smA = (char*)As;
  char* smB = (char*)Bs;

  const int tid  = threadIdx.x;
  const int lane = tid & 63;
  const int w    = tid >> 6;
  const int wm   = w >> 2;           // 0..1
  const int wn   = w & 3;            // 0..3
  const int NT   = K >> 6;

  // T1: XCD-aware tile swizzle (all grids have nwg % 8 == 0)
  const int nwg = gridDim.x * gridDim.y;
  const int f   = blockIdx.y * gridDim.x + blockIdx.x;
  const int sw  = (f & 7) * (nwg >> 3) + (f >> 3);
  const long tm = (long)(sw / gridDim.x) * 256;
  const long tn = (long)(sw % gridDim.x) * 256;

  // staging addressing: thread covers 16B chunk; pre-swizzled source col (T2)
  const int r0 = tid >> 3;                 // row within 128-row half
  const int c0 = (tid & 7) ^ (r0 & 7);
  const short* aS = A + (tm + r0) * (long)K + c0 * 8;
  const short* bS = B + (tn + r0) * (long)K + c0 * 8;
  const int ldsW0 = w * 1024;
  const int ldsW1 = 8192 + w * 1024;
  const long halfR = 128 * (long)K;

  auto stgA = [&](int dstoff, const short* srcp){
    __builtin_amdgcn_global_load_lds((const __attribute__((address_space(1))) void*)(srcp),
        (__attribute__((address_space(3))) void*)(smA + dstoff + ldsW0), 16, 0, 0);
    __builtin_amdgcn_global_load_lds((const __attribute__((address_space(1))) void*)(srcp + 64 * (long)K),
        (__attribute__((address_space(3))) void*)(smA + dstoff + ldsW1), 16, 0, 0);
  };
  auto stgB = [&](int dstoff, const short* srcp){
    __builtin_amdgcn_global_load_lds((const __attribute__((address_space(1))) void*)(srcp),
        (__attribute__((address_space(3))) void*)(smB + dstoff + ldsW0), 16, 0, 0);
    __builtin_amdgcn_global_load_lds((const __attribute__((address_space(1))) void*)(srcp + 64 * (long)K),
        (__attribute__((address_space(3))) void*)(smB + dstoff + ldsW1), 16, 0, 0);
  };

  f32x4 acc[8][4];
  #pragma unroll
  for (int i = 0; i < 8; i++)
    #pragma unroll
    for (int j = 0; j < 4; j++)
      acc[i][j] = (f32x4){0.f, 0.f, 0.f, 0.f};

  // read-side addressing (swizzle = same involution as pre-swizzled source)
  const int rb   = (lane & 15) * 128;
  const int ct0  = (((lane >> 4)    ) ^ (lane & 7)) * 16;
  const int ct1  = ((4 + (lane >> 4)) ^ (lane & 7)) * 16;
  const int aoff = wm * 16384 + rb;
  const int boff = wn * 8192 + rb;

  // ---- prologue: tile0 (B0,B1,A0,A1) then tile1 (B0,B1); vmcnt(4) -> tile0 landed ----
  stgB(0, bS);              stgB(16384, bS + halfR);
  stgA(0, aS);              stgA(16384, aS + halfR);
  stgB(32768, bS + 64);     stgB(32768 + 16384, bS + halfR + 64);
  asm volatile("s_waitcnt vmcnt(4)" ::: "memory");
  __builtin_amdgcn_s_barrier();

  for (int t = 0; t < NT; ++t){
    const int cur = (t & 1) * 32768;
    const int nxt = 32768 - cur;
    const bool s1 = (t + 1 < NT), s2 = (t + 2 < NT);
    const long o1 = (long)(t + 1) * 64, o2 = (long)(t + 2) * 64;
    short8 a[4], bb[4];

    // ---- phase 1: read B kk0 + A mi0-3 kk0; stage A0(t+1)->nxt ----
    #pragma unroll
    for (int ni = 0; ni < 4; ni++)
      bb[ni] = *(const short8*)(smB + cur + boff + ni * 2048 + ct0);
    #pragma unroll
    for (int q = 0; q < 4; q++)
      a[q] = *(const short8*)(smA + cur + aoff + q * 2048 + ct0);
    if (s1) stgA(nxt, aS + o1);
    __builtin_amdgcn_s_barrier();
    asm volatile("s_waitcnt lgkmcnt(0)" ::: "memory");
    __builtin_amdgcn_sched_barrier(0);
    __builtin_amdgcn_s_setprio(1);
    #pragma unroll
    for (int q = 0; q < 4; q++)
      #pragma unroll
      for (int ni = 0; ni < 4; ni++)
        acc[q][ni] = MFMA16(a[q], bb[ni], acc[q][ni], 0, 0, 0);
    __builtin_amdgcn_s_setprio(0);
    __builtin_amdgcn_s_barrier();

    // ---- phase 2: read A mi4-7 kk0; stage A1(t+1)->nxt ----
    #pragma unroll
    for (int q = 0; q < 4; q++)
      a[q] = *(const short8*)(smA + cur + aoff + (4 + q) * 2048 + ct0);
    if (s1) stgA(nxt + 16384, aS + halfR + o1);
    __builtin_amdgcn_s_barrier();
    asm volatile("s_waitcnt lgkmcnt(0)" ::: "memory");
    __builtin_amdgcn_sched_barrier(0);
    __builtin_amdgcn_s_setprio(1);
    #pragma unroll
    for (int q = 0; q < 4; q++)
      #pragma unroll
      for (int ni = 0; ni < 4; ni++)
        acc[4 + q][ni] = MFMA16(a[q], bb[ni], acc[4 + q][ni], 0, 0, 0);
    __builtin_amdgcn_s_setprio(0);
    __builtin_amdgcn_s_barrier();

    // ---- phase 3: read B kk1 + A mi0-3 kk1 (no stage) ----
    #pragma unroll
    for (int ni = 0; ni < 4; ni++)
      bb[ni] = *(const short8*)(smB + cur + boff + ni * 2048 + ct1);
    #pragma unroll
    for (int q = 0; q < 4; q++)
      a[q] = *(const short8*)(smA + cur + aoff + q * 2048 + ct1);
    __builtin_amdgcn_s_barrier();
    asm volatile("s_waitcnt lgkmcnt(0)" ::: "memory");
    __builtin_amdgcn_sched_barrier(0);
    __builtin_amdgcn_s_setprio(1);
    #pragma unroll
    for (int q = 0; q < 4; q++)
      #pragma unroll
      for (int ni = 0; ni < 4; ni++)
        acc[q][ni] = MFMA16(a[q], bb[ni], acc[q][ni], 0, 0, 0);
    __builtin_amdgcn_s_setprio(0);
    __builtin_amdgcn_s_barrier();

    // ---- phase 4: read A mi4-7 kk1; stage B0+B1(t+2)->cur; vmcnt; publish ----
    #pragma unroll
    for (int q = 0; q < 4; q++)
      a[q] = *(const short8*)(smA + cur + aoff + (4 + q) * 2048 + ct1);
    if (s2){ stgB(cur, bS + o2); stgB(cur + 16384, bS + halfR + o2); }
    __builtin_amdgcn_s_barrier();
    asm volatile("s_waitcnt lgkmcnt(0)" ::: "memory");
    __builtin_amdgcn_sched_barrier(0);
    __builtin_amdgcn_s_setprio(1);
    #pragma unroll
    for (int q = 0; q < 4; q++)
      #pragma unroll
      for (int ni = 0; ni < 4; ni++)
        acc[4 + q][ni] = MFMA16(a[q], bb[ni], acc[4 + q][ni], 0, 0, 0);
    __builtin_amdgcn_s_setprio(0);
    if (s2) asm volatile("s_waitcnt vmcnt(4)" ::: "memory");
    else    asm volatile("s_waitcnt vmcnt(0)" ::: "memory");
    __builtin_amdgcn_s_barrier();
  }

  // ---- epilogue ----
  #pragma unroll
  for (int mi = 0; mi < 8; mi++){
    if (EPI == 3){
      #pragma unroll
      for (int p = 0; p < 2; p++){
        #pragma unroll
        for (int v = 0; v < 4; v++){
          long row = tm + wm * 128 + mi * 16 + (lane >> 4) * 4 + v;
          long col = (tn >> 1) + wn * 32 + p * 16 + (lane & 15);
          float u = acc[mi][2 * p][v];
          float g = acc[mi][2 * p + 1][v];
          Cbf[row * ldcb + col] = f2bf(u * g * gelu_phi(g));
        }
      }
    } else {
      #pragma unroll
      for (int ni = 0; ni < 4; ni++){
        #pragma unroll
        for (int v = 0; v < 4; v++){
          long row = tm + wm * 128 + mi * 16 + (lane >> 4) * 4 + v;
          long col = tn + wn * 64 + ni * 16 + (lane & 15);
          float x = acc[mi][ni][v];
          if (EPI == 0){
            Cbf[row * ldcb + col] = f2bf(x);
          } else if (EPI == 1){
            Cres[row * 512 + col] = x + Cres[row * 512 + col];
          } else {
            float rr = x + Cres[row * 512 + col];
            Cres[row * 512 + col] = rr;
            Cbf[row * 512 + col] = f2bf(rr);
          }
        }
      }
    }
  }
}

// ---------------- local attention ----------------
// grid (32 windows, 8 heads, 8 batch), 256 threads (4 waves x 32 q-rows)
__global__ __launch_bounds__(256, 2)
void attn_kernel(const short* __restrict__ qkv, short* __restrict__ o)
{
  __shared__ short Ks[128 * 64];     // swizzled [key][d]
  __shared__ short Vt[64 * 136];     // [d][key], stride 136
  __shared__ short Ps[4 * 32 * 128]; // per-wave swizzled P
  const int win = blockIdx.x, hh = blockIdx.y, b = blockIdx.z;
  const int tid = threadIdx.x, lane = tid & 63, w = tid >> 6;
  const long qrow0 = (long)b * 4096 + (long)win * 128;

  short8 qf[2][2];
  #pragma unroll
  for (int i = 0; i < 2; i++)
    #pragma unroll
    for (int kk = 0; kk < 2; kk++)
      qf[i][kk] = *(const short8*)(qkv + (qrow0 + w * 32 + i * 16 + (lane & 15)) * 1536
                                   + hh * 64 + kk * 32 + (lane >> 4) * 8);

  f32x4 oacc[2][4];
  #pragma unroll
  for (int i = 0; i < 2; i++)
    #pragma unroll
    for (int j = 0; j < 4; j++)
      oacc[i][j] = (f32x4){0.f, 0.f, 0.f, 0.f};
  float rs[2][4];
  #pragma unroll
  for (int i = 0; i < 2; i++)
    #pragma unroll
    for (int v = 0; v < 4; v++)
      rs[i][v] = 0.f;

  const int row_s = tid >> 3, c_s = tid & 7;
  for (int cc = 0; cc < 3; cc++){
    int kw = win - 1 + cc;
    if (kw < 0 || kw >= 32) continue;
    const long krow0 = (long)b * 4096 + (long)kw * 128;
    __syncthreads();
    #pragma unroll
    for (int r = 0; r < 4; r++){
      int row = row_s + r * 32;
      const short* src = qkv + (krow0 + row) * 1536 + hh * 64;
      short8 kv = *(const short8*)(src + 512 + c_s * 8);
      *(short8*)((char*)Ks + ((row * 128 + c_s * 16) ^ ((row & 7) << 4))) = kv;
      short8 vv = *(const short8*)(src + 1024 + c_s * 8);
      #pragma unroll
      for (int e = 0; e < 8; e++) Vt[(c_s * 8 + e) * 136 + row] = vv[e];
    }
    __syncthreads();

    f32x4 sacc[2][8];
    #pragma unroll
    for (int i = 0; i < 2; i++)
      #pragma unroll
      for (int j = 0; j < 8; j++)
        sacc[i][j] = (f32x4){0.f, 0.f, 0.f, 0.f};
    #pragma unroll
    for (int kk = 0; kk < 2; kk++){
      short8 bbk[8];
      int ac = (kk * 32 + (lane >> 4) * 8) * 2;
      #pragma unroll
      for (int j = 0; j < 8; j++){
        int br = j * 16 + (lane & 15);
        bbk[j] = *(const short8*)((char*)Ks + ((br * 128 + ac) ^ ((br & 7) << 4)));
      }
      #pragma unroll
      for (int i = 0; i < 2; i++)
        #pragma unroll
        for (int j = 0; j < 8; j++)
          sacc[i][j] = MFMA16(qf[i][kk], bbk[j], sacc[i][j], 0, 0, 0);
    }

    short* myPs = Ps + w * 32 * 128;
    float psum[2][4];
    #pragma unroll
    for (int i = 0; i < 2; i++)
      #pragma unroll
      for (int v = 0; v < 4; v++)
        psum[i][v] = 0.f;
    #pragma unroll
    for (int i = 0; i < 2; i++)
      #pragma unroll
      for (int j = 0; j < 8; j++)
        #pragma unroll
        for (int v = 0; v < 4; v++){
          float p = expf(0.125f * sacc[i][j][v]);
          psum[i][v] += p;
          int prow = i * 16 + (lane >> 4) * 4 + v;
          int pcb  = (j * 16 + (lane & 15)) * 2;
          *(short*)((char*)myPs + ((prow * 256 + pcb) ^ ((prow & 7) << 4))) = f2bf(p);
        }
    #pragma unroll
    for (int i = 0; i < 2; i++)
      #pragma unroll
      for (int v = 0; v < 4; v++){
        float s = psum[i][v];
        s += __shfl_xor(s, 1); s += __shfl_xor(s, 2);
        s += __shfl_xor(s, 4); s += __shfl_xor(s, 8);
        rs[i][v] += s;
      }
    __syncthreads();

    #pragma unroll
    for (int kk = 0; kk < 4; kk++){
      short8 pa[2], vb[4];
      int kb = (kk * 32 + (lane >> 4) * 8) * 2;
      #pragma unroll
      for (int i = 0; i < 2; i++){
        int pr = i * 16 + (lane & 15);
        pa[i] = *(const short8*)((char*)myPs + ((pr * 256 + kb) ^ ((pr & 7) << 4)));
      }
      #pragma unroll
      for (int j = 0; j < 4; j++){
        int vr = j * 16 + (lane & 15);
        vb[j] = *(const short8*)((char*)Vt + (vr * 272 + kb));
      }
      #pragma unroll
      for (int i = 0; i < 2; i++)
        #pragma unroll
        for (int j = 0; j < 4; j++)
          oacc[i][j] = MFMA16(pa[i], vb[j], oacc[i][j], 0, 0, 0);
    }
  }

  #pragma unroll
  for (int i = 0; i < 2; i++)
    #pragma unroll
    for (int j = 0; j < 4; j++)
      #pragma unroll
      for (int v = 0; v < 4; v++){
        long row = qrow0 + w * 32 + i * 16 + (lane >> 4) * 4 + v;
        int col = hh * 64 + j * 16 + (lane & 15);
        o[row * 512 + col] = f2bf(oacc[i][j][v] / rs[i][v]);
      }
}

// ---------------- layernorm (one wave per row) ----------------
__global__ __launch_bounds__(256)
void ln_kernel(const float* __restrict__ h, const float* __restrict__ g,
               const float* __restrict__ be, short* __restrict__ y)
{
  long row = (long)blockIdx.x * 4 + (threadIdx.x >> 6);
  int lane = threadIdx.x & 63;
  const float* x = h + row * 512 + lane * 8;
  float4 a0 = *(const float4*)x;
  float4 a1 = *(const float4*)(x + 4);
  float v[8] = {a0.x, a0.y, a0.z, a0.w, a1.x, a1.y, a1.z, a1.w};
  float s = 0.f, sq = 0.f;
  #pragma unroll
  for (int j = 0; j < 8; j++){ s += v[j]; sq += v[j] * v[j]; }
  #pragma unroll
  for (int m = 1; m <= 32; m <<= 1){ s += __shfl_xor(s, m); sq += __shfl_xor(sq, m); }
  float mu = s * (1.f / 512.f);
  float var = sq * (1.f / 512.f) - mu * mu;
  float rstd = rsqrtf(var + 1e-5f);
  short* yo = y + row * 512 + lane * 8;
  #pragma unroll
  for (int j = 0; j < 8; j++){
    int c = lane * 8 + j;
    yo[j] = f2bf((v[j] - mu) * rstd * g[c] + be[c]);
  }
}

// ---------------- mean pool + classifier ----------------
__global__ void pool_partial(const float* __restrict__ h, float* __restrict__ part){
  int b = blockIdx.x, ch = blockIdx.y, t = threadIdx.x;
  float s0 = 0.f, s1 = 0.f;
  const float* base = h + ((long)b * 4096 + ch * 128) * 512;
  for (int n = 0; n < 128; n++){
    s0 += base[(long)n * 512 + t];
    s1 += base[(long)n * 512 + t + 256];
  }
  part[((b * 32 + ch) * 512) + t] = s0;
  part[((b * 32 + ch) * 512) + t + 256] = s1;
}

__global__ void pool_proj(const float* __restrict__ part, const float* __restrict__ pw,
                          const float* __restrict__ pb, float* __restrict__ out){
  __shared__ float pooled[512];
  __shared__ float red[4];
  int b = blockIdx.x, t = threadIdx.x;
  int lane = t & 63, w = t >> 6;
  float s0 = 0.f, s1 = 0.f;
  for (int ch = 0; ch < 32; ch++){
    s0 += part[((b * 32 + ch) * 512) + t];
    s1 += part[((b * 32 + ch) * 512) + t + 256];
  }
  pooled[t] = s0 * (1.f / 4096.f);
  pooled[t + 256] = s1 * (1.f / 4096.f);
  __syncthreads();
  for (int cls = 0; cls < 10; cls++){
    float p = pooled[t] * pw[cls * 512 + t] + pooled[t + 256] * pw[cls * 512 + t + 256];
    p += __shfl_xor(p, 1); p += __shfl_xor(p, 2); p += __shfl_xor(p, 4);
    p += __shfl_xor(p, 8); p += __shfl_xor(p, 16); p += __shfl_xor(p, 32);
    if (lane == 0) red[w] = p;
    __syncthreads();
    if (t == 0) out[b * 10 + cls] = red[0] + red[1] + red[2] + red[3] + pb[cls];
    __syncthreads();
  }
}

extern "C" void kernel_launch(void* const* d_in, const int* in_sizes, int n_in,
                              void* d_out, int out_size, void* d_ws, size_t ws_size,
                              hipStream_t stream)
{
  const float* x      = (const float*)d_in[0];
  const float* lin_w  = (const float*)d_in[1];
  const float* lin_b  = (const float*)d_in[2];
  const float* qkvw_f = (const float*)d_in[3];
  const float* outw_f = (const float*)d_in[4];
  const float* lng    = (const float*)d_in[5];
  const float* lnb    = (const float*)d_in[6];
  const float* w1_f   = (const float*)d_in[7];
  const float* w2_f   = (const float*)d_in[8];
  const float* projw  = (const float*)d_in[9];
  const float* projb  = (const float*)d_in[10];
  float* out = (float*)d_out;

  char* ws = (char*)d_ws;
  float* hf32 = (float*)(ws);                    // 32768*512*4  = 64 MiB
  short* abuf = (short*)(ws + 67108864);         // 32768*512*2  = 32 MiB
  short* qkvb = (short*)(ws + 100663296);        // 32768*1536*2 = 96 MiB (shared with gbuf)
  short* gbuf = qkvb;                            // 32768*1408*2 = 88 MiB
  short* obuf = (short*)(ws + 201326592);        // 32 MiB
  float* part = (float*)(ws + 234881024);        // 8*32*512*4
  short* wqkv = (short*)(ws + 235405312);        // 4*1536*512*2
  short* wout = (short*)(ws + 247988224);        // 4*512*512*2
  short* w1p  = (short*)(ws + 250085376);        // 4*2816*512*2
  short* w2p  = (short*)(ws + 261619712);        // 4*512*1408*2 (end 267386880)

  cast_bf16_kernel<<<12288, 256, 0, stream>>>(qkvw_f, wqkv, 4 * 1536 * 512);
  cast_bf16_kernel<<<4096, 256, 0, stream>>>(outw_f, wout, 4 * 512 * 512);
  w1p_kernel<<<22528, 256, 0, stream>>>(w1_f, w1p);
  w2p_kernel<<<11264, 256, 0, stream>>>(w2_f, w2p);
  embed_kernel<<<8192, 256, 0, stream>>>(x, lin_w, lin_b, hf32, abuf);

  for (int l = 0; l < 4; l++){
    gemm256<0><<<dim3(6, 128), 512, 0, stream>>>(abuf, wqkv + (size_t)l * 1536 * 512, 512,
                                                 nullptr, qkvb, 1536);
    attn_kernel<<<dim3(32, 8, 8), 256, 0, stream>>>(qkvb, obuf);
    gemm256<1><<<dim3(2, 128), 512, 0, stream>>>(obuf, wout + (size_t)l * 512 * 512, 512,
                                                 hf32, nullptr, 0);
    ln_kernel<<<8192, 256, 0, stream>>>(hf32, lng + l * 512, lnb + l * 512, abuf);
    gemm256<3><<<dim3(11, 128), 512, 0, stream>>>(abuf, w1p + (size_t)l * 2816 * 512, 512,
                                                  nullptr, gbuf, 1408);
    gemm256<2><<<dim3(2, 128), 512, 0, stream>>>(gbuf, w2p + (size_t)l * 512 * 1408, 1408,
                                                 hf32, abuf, 512);
  }
  pool_partial<<<dim3(8, 32), 256, 0, stream>>>(hf32, part);
  pool_proj<<<8, 256, 0, stream>>>(part, projw, projb, out);
}